// Round 1
// baseline (807.117 us; speedup 1.0000x reference)
//
#include <hip/hip_runtime.h>
#include <math.h>

#define D_DIM 512
#define K_DIM 112
#define TOPK  5
#define LAMBDA_ 5.0f

#define BM 128          // rows per block
#define BK 64           // D-chunk staged in LDS (x only)
#define TM 8            // rows per thread
#define TN 14           // clusters per thread
#define NTHREADS 128    // 16 row-groups (tx) x 8 cluster-groups (ky)
#define XS_LD 132       // x-tile row stride (floats): 16B-aligned rows
#define CT_LD 128       // padded C^T row: cluster k at (k/14)*16 + k%14
#define NCAND (8 * TOPK)   // 40 candidates per row (8 ky-groups x top-5)
#define CAND_LD 41         // +1 pad -> odd stride, conflict-free column scan

// C^T with per-ky-group padding so each thread's 14 clusters are two aligned
// float4 groups. 512*128*4 = 256 KiB device-global (C is L2-resident anyway).
__device__ float g_ct[D_DIM * CT_LD];

__global__ __launch_bounds__(128)
void transpose_c(const float* __restrict__ cc) {
  const int d = blockIdx.x;      // 0..511
  const int k = threadIdx.x;     // 0..127
  if (k < K_DIM)
    g_ct[d * CT_LD + (k / TN) * 16 + (k % TN)] = cc[k * D_DIM + d];
}

struct __align__(16) SMem {
  union {
    // x tile, transposed + XOR-swizzled: (d,r) -> xs[d*XS_LD + (r ^ ((d>>3&7)<<2))]
    // swizzle => 2-way max bank aliasing on BOTH scalar staging writes and b128 reads
    float xs[BK * XS_LD];                    // 33792 B
    struct {
      float         cv[BM][CAND_LD];         // 20992 B candidate values (8 sorted 5-lists)
      unsigned char ci[BM][CAND_LD];         // 5248 B candidate cluster ids
      float         sc[BM][TOPK];            // 2560 B lambda * softmax weight
      int           si[BM][TOPK];            // 2560 B final top-5 ids
    } p;                                     // 31360 B < 33792 -> union = 33792 B
  } u;                                       // 4 blocks/CU (135 KiB of 160)
};

__global__ __launch_bounds__(NTHREADS, 2)
void tse_fused(const float* __restrict__ x, const float* __restrict__ cc,
               float* __restrict__ out) {
  __shared__ SMem sm;
  const int tid = threadIdx.x;
  const int ky  = tid & 7;        // cluster group: clusters ky*14 .. +13
  const int tx  = tid >> 3;       // row group: rows tx*8 .. +7
  const long long row0 = (long long)blockIdx.x * BM;

  float acc[TM][TN];
#pragma unroll
  for (int i = 0; i < TM; ++i)
#pragma unroll
    for (int j = 0; j < TN; ++j) acc[i][j] = 0.0f;

#pragma unroll 1
  for (int dc = 0; dc < D_DIM; dc += BK) {
    // ---- stage x tile: 16 coalesced float4 loads, swizzled scalar LDS writes ----
    // rho(d) = ((d>>3)&7)<<2 ; for the 4 rows of one float4, d>>3 == dg>>1 (const)
#pragma unroll
    for (int it = 0; it < (BM * BK / 4) / NTHREADS; ++it) {  // 16
      int t  = it * NTHREADS + tid;
      int dg = t & 15;                 // float4 column group (d = dg*4+q)
      int r  = t >> 4;                 // row
      float4 v = *(const float4*)(x + (row0 + r) * D_DIM + dc + dg * 4);
      int d0 = dg * 4;
      int rw = r ^ (((dg >> 1) & 7) << 2);
      sm.u.xs[(d0 + 0) * XS_LD + rw] = v.x;
      sm.u.xs[(d0 + 1) * XS_LD + rw] = v.y;
      sm.u.xs[(d0 + 2) * XS_LD + rw] = v.z;
      sm.u.xs[(d0 + 3) * XS_LD + rw] = v.w;
    }
    __syncthreads();

    const float* ctp = g_ct + dc * CT_LD + ky * 16;
    // ---- inner loop: 112 FMA per d, only x from LDS (2xb128, 2-way max),
    //      C from global/L1 (L2-resident, 4 coalesced float4 per thread) ----
#pragma unroll 4
    for (int dl = 0; dl < BK; ++dl) {
      const int rho = ((dl >> 3) & 7) << 2;
      const float* xrow = &sm.u.xs[dl * XS_LD];
      const int off = (tx * TM) ^ rho;           // XOR cancels on readback:
      float4 xa = *(const float4*)(xrow + off);        // rows tx*8 .. +3
      float4 xb = *(const float4*)(xrow + (off ^ 4));  // rows tx*8+4 .. +7
      float xf[TM] = {xa.x, xa.y, xa.z, xa.w, xb.x, xb.y, xb.z, xb.w};
      const float4* cp = (const float4*)(ctp + dl * CT_LD);
      float4 c0 = cp[0], c1 = cp[1], c2 = cp[2], c3 = cp[3];
      float cf[TN] = {c0.x, c0.y, c0.z, c0.w, c1.x, c1.y, c1.z, c1.w,
                      c2.x, c2.y, c2.z, c2.w, c3.x, c3.y};
#pragma unroll
      for (int i = 0; i < TM; ++i)
#pragma unroll
        for (int j = 0; j < TN; ++j)
          acc[i][j] = fmaf(xf[i], cf[j], acc[i][j]);
    }
    __syncthreads();  // also protects union re-use after the last chunk
  }

  // ---- per-thread top-5 of its 14 clusters, per row (exact: any global top-5
  //      element is in its ky-block's top-5); strict > keeps lowest idx on ties
#pragma unroll
  for (int i = 0; i < TM; ++i) {
    float tv[TOPK]; int ti[TOPK];
#pragma unroll
    for (int s = 0; s < TOPK; ++s) { tv[s] = -3.0e38f; ti[s] = 0; }
#pragma unroll
    for (int j = 0; j < TN; ++j) {
      float v = acc[i][j];
      if (v > tv[TOPK - 1]) {
        tv[TOPK - 1] = v; ti[TOPK - 1] = ky * TN + j;
#pragma unroll
        for (int s = TOPK - 2; s >= 0; --s) {
          if (tv[s + 1] > tv[s]) {
            float tf = tv[s]; tv[s] = tv[s + 1]; tv[s + 1] = tf;
            int   tq = ti[s]; ti[s] = ti[s + 1]; ti[s + 1] = tq;
          }
        }
      }
    }
    int r = tx * TM + i;
#pragma unroll
    for (int s = 0; s < TOPK; ++s) {
      sm.u.p.cv[r][ky * TOPK + s] = tv[s];
      sm.u.p.ci[r][ky * TOPK + s] = (unsigned char)ti[s];
    }
  }
  __syncthreads();

  // ---- merge the 8 sorted 5-lists per row (thread == row), softmax ----
  // scanning c ascending == ascending ky == ascending idx -> lax.top_k tie rule
  {
    const int r = tid;   // NTHREADS == BM
    float tv[TOPK]; int ti[TOPK];
#pragma unroll
    for (int s = 0; s < TOPK; ++s) { tv[s] = -3.0e38f; ti[s] = 0; }
    for (int c = 0; c < NCAND; ++c) {
      float v = sm.u.p.cv[r][c];       // stride 41 (odd) -> conflict-free
      if (v > tv[TOPK - 1]) {
        tv[TOPK - 1] = v; ti[TOPK - 1] = (int)sm.u.p.ci[r][c];
#pragma unroll
        for (int s = TOPK - 2; s >= 0; --s) {
          if (tv[s + 1] > tv[s]) {
            float tf = tv[s]; tv[s] = tv[s + 1]; tv[s + 1] = tf;
            int   tq = ti[s]; ti[s] = ti[s + 1]; ti[s + 1] = tq;
          }
        }
      }
    }
    float m = tv[0];                   // sorted descending -> max
    float e[TOPK]; float z = 0.0f;
#pragma unroll
    for (int s = 0; s < TOPK; ++s) { e[s] = __expf(tv[s] - m); z += e[s]; }
    float sl = LAMBDA_ / z;
#pragma unroll
    for (int s = 0; s < TOPK; ++s) { sm.u.p.sc[r][s] = e[s] * sl; sm.u.p.si[r][s] = ti[s]; }
  }
  __syncthreads();

  // ---- epilogue: out = x + sum_k sc_k * C[si_k]; sc/si broadcast, C coalesced ----
  {
    const int dg = tid;   // float4 column 0..127
    for (int r = 0; r < BM; ++r) {
      const long long base = (row0 + r) * D_DIM + dg * 4;
      float4 o = *(const float4*)(x + base);
#pragma unroll
      for (int t = 0; t < TOPK; ++t) {
        float w  = sm.u.p.sc[r][t];
        int   ix = sm.u.p.si[r][t];
        const float4 cv = *(const float4*)(cc + (long long)ix * D_DIM + dg * 4);
        o.x = fmaf(w, cv.x, o.x);
        o.y = fmaf(w, cv.y, o.y);
        o.z = fmaf(w, cv.z, o.z);
        o.w = fmaf(w, cv.w, o.w);
      }
      *(float4*)(out + base) = o;
    }
  }
}

extern "C" void kernel_launch(void* const* d_in, const int* in_sizes, int n_in,
                              void* d_out, int out_size, void* d_ws, size_t ws_size,
                              hipStream_t stream) {
  const float* x  = (const float*)d_in[0];
  const float* cc = (const float*)d_in[1];
  float* out = (float*)d_out;
  const int Btot = in_sizes[0] / D_DIM;   // 131072 (elements / D)
  const int grid = Btot / BM;             // 1024 == 4 blocks/CU x 256 CU, no tail
  transpose_c<<<dim3(D_DIM), dim3(128), 0, stream>>>(cc);
  tse_fused<<<dim3(grid), dim3(NTHREADS), 0, stream>>>(x, cc, out);
}

// Round 2
// 725.695 us; speedup vs baseline: 1.1122x; 1.1122x over previous
//
#include <hip/hip_runtime.h>
#include <math.h>

#define D_DIM 512
#define K_DIM 112
#define TOPK  5
#define LAMBDA_ 5.0f

#define BM 128          // rows per block
#define BK 64           // D-chunk staged in LDS (x only)
#define NTHREADS 256    // 4 waves
#define KPW 28          // clusters per wave: 4 * 28 = 112 exactly
#define CT_LD 128       // C^T row stride (floats); wave w's 28 floats at w*32 (16B aligned)
#define XS_LD 132       // x-tile row stride (floats)
#define NCAND (4 * TOPK)   // 20 candidates per row
#define CAND_LD 21         // odd stride -> conflict-free scan

#define CT_BYTES (D_DIM * CT_LD * sizeof(float))

// fallback C^T storage if workspace is too small (static => internal linkage)
static __device__ float g_ct_fallback[D_DIM * CT_LD];

__global__ __launch_bounds__(128)
void transpose_c(const float* __restrict__ cc, float* __restrict__ ct) {
  const int d = blockIdx.x;      // 0..511
  const int k = threadIdx.x;     // 0..127
  if (k < K_DIM)
    ct[d * CT_LD + (k / KPW) * 32 + (k % KPW)] = cc[k * D_DIM + d];
}

struct __align__(16) SMem {
  union {
    // x tile, transposed + XOR-swizzled: (d,r) -> xs[d*XS_LD + (r ^ ((d>>3&7)<<2))]
    // proven in round 1: staging writes AND reads land at <= 2-way (free)
    float xs[BK * XS_LD];                    // 33792 B  -> 4 blocks/CU
    struct {
      float         cv[BM][CAND_LD];         // 10752 B  candidate values (4 sorted 5-lists)
      float         sc[BM][TOPK];            // 2560 B   lambda * softmax weight
      int           si[BM][TOPK];            // 2560 B   final top-5 ids
      unsigned char ci[BM][24];              // 3072 B   candidate cluster ids
    } p;                                     // 18944 B < 33792
  } u;
};

__global__ __launch_bounds__(NTHREADS, 4)
void tse_fused(const float* __restrict__ x, const float* __restrict__ cc,
               const float* __restrict__ ct, float* __restrict__ out) {
  __shared__ SMem sm;
  const int tid  = threadIdx.x;
  const int lane = tid & 63;
  // wave id, pinned uniform so all C addresses are provably scalar
  const int w = __builtin_amdgcn_readfirstlane(tid >> 6);
  const long long row0 = (long long)blockIdx.x * BM;

  // lane owns rows (2*lane, 2*lane+1); wave owns clusters w*28 .. w*28+27
  float acc[2][KPW];
#pragma unroll
  for (int i = 0; i < 2; ++i)
#pragma unroll
    for (int j = 0; j < KPW; ++j) acc[i][j] = 0.0f;

#pragma unroll 1
  for (int dc = 0; dc < D_DIM; dc += BK) {
    // ---- stage x tile: 8 coalesced float4 loads/thread, swizzled LDS writes ----
#pragma unroll
    for (int it = 0; it < (BM * BK / 4) / NTHREADS; ++it) {  // 8
      int t  = it * NTHREADS + tid;
      int dg = t & 15;                 // float4 column group (d = dg*4+q)
      int r  = t >> 4;                 // row
      float4 v = *(const float4*)(x + (row0 + r) * D_DIM + dc + dg * 4);
      int d0 = dg * 4;
      int rw = r ^ (((dg >> 1) & 7) << 2);   // same swizzle as read (d>>3 == dg>>1)
      sm.u.xs[(d0 + 0) * XS_LD + rw] = v.x;
      sm.u.xs[(d0 + 1) * XS_LD + rw] = v.y;
      sm.u.xs[(d0 + 2) * XS_LD + rw] = v.z;
      sm.u.xs[(d0 + 3) * XS_LD + rw] = v.w;
    }
    __syncthreads();

    const float* ctp = ct + (long long)dc * CT_LD + w * 32;  // uniform per wave
    // ---- inner loop: 56 FMA per d per lane; x: one b64 from LDS (conflict-free),
    //      C: 28 floats from wave-uniform address -> SGPRs via SMEM ----
#pragma unroll 4
    for (int dl = 0; dl < BK; ++dl) {
      const int s = ((dl >> 3) & 7) << 2;
      const float2 xr = *(const float2*)&sm.u.xs[dl * XS_LD + ((2 * lane) ^ s)];
      const float* cp = ctp + dl * CT_LD;    // uniform
      float cf[KPW];
#pragma unroll
      for (int j = 0; j < KPW; ++j) cf[j] = cp[j];
#pragma unroll
      for (int j = 0; j < KPW; ++j) {
        acc[0][j] = fmaf(xr.x, cf[j], acc[0][j]);   // v_fmac_f32 v, s, v
        acc[1][j] = fmaf(xr.y, cf[j], acc[1][j]);
      }
    }
    __syncthreads();  // also protects union re-use after the last chunk
  }

  // ---- per-lane top-5 of its 28 clusters, for each of its 2 rows ----
  // exact: any global top-5 element is in its wave-block's top-5
  // strict > with ascending j (ascending global index) == lax.top_k tie rule
#pragma unroll
  for (int i = 0; i < 2; ++i) {
    float tv[TOPK]; int ti[TOPK];
#pragma unroll
    for (int s = 0; s < TOPK; ++s) { tv[s] = -3.0e38f; ti[s] = 0; }
#pragma unroll
    for (int j = 0; j < KPW; ++j) {
      float v = acc[i][j];
      if (v > tv[TOPK - 1]) {
        tv[TOPK - 1] = v; ti[TOPK - 1] = w * KPW + j;
#pragma unroll
        for (int s = TOPK - 2; s >= 0; --s) {
          if (tv[s + 1] > tv[s]) {
            float tf = tv[s]; tv[s] = tv[s + 1]; tv[s + 1] = tf;
            int   tq = ti[s]; ti[s] = ti[s + 1]; ti[s + 1] = tq;
          }
        }
      }
    }
    const int r = 2 * lane + i;
#pragma unroll
    for (int s = 0; s < TOPK; ++s) {
      sm.u.p.cv[r][w * TOPK + s] = tv[s];
      sm.u.p.ci[r][w * TOPK + s] = (unsigned char)ti[s];
    }
  }
  __syncthreads();

  // ---- merge the 4 sorted 5-lists per row (thread == row), softmax ----
  // scanning c ascending == ascending wave == ascending cluster idx (tie rule ok)
  if (tid < BM) {
    const int r = tid;
    float tv[TOPK]; int ti[TOPK];
#pragma unroll
    for (int s = 0; s < TOPK; ++s) { tv[s] = -3.0e38f; ti[s] = 0; }
#pragma unroll
    for (int c = 0; c < NCAND; ++c) {
      float v = sm.u.p.cv[r][c];           // stride 21 (odd) -> conflict-free
      if (v > tv[TOPK - 1]) {
        tv[TOPK - 1] = v; ti[TOPK - 1] = (int)sm.u.p.ci[r][c];
#pragma unroll
        for (int s = TOPK - 2; s >= 0; --s) {
          if (tv[s + 1] > tv[s]) {
            float tf = tv[s]; tv[s] = tv[s + 1]; tv[s + 1] = tf;
            int   tq = ti[s]; ti[s] = ti[s + 1]; ti[s + 1] = tq;
          }
        }
      }
    }
    float m = tv[0];                        // sorted descending -> max
    float e[TOPK]; float z = 0.0f;
#pragma unroll
    for (int s = 0; s < TOPK; ++s) { e[s] = __expf(tv[s] - m); z += e[s]; }
    float sl = LAMBDA_ / z;
#pragma unroll
    for (int s = 0; s < TOPK; ++s) { sm.u.p.sc[r][s] = e[s] * sl; sm.u.p.si[r][s] = ti[s]; }
  }
  __syncthreads();

  // ---- epilogue: out = x + sum_k sc_k * C[si_k]; coalesced float4 sweep ----
  {
    const int dg = tid & 127;        // float4 column within row (D/4 = 128)
    int r = tid >> 7;                // 0 or 1
    for (; r < BM; r += 2) {
      const long long base = (row0 + r) * D_DIM + dg * 4;
      float4 o = *(const float4*)(x + base);
#pragma unroll
      for (int t = 0; t < TOPK; ++t) {
        float w2 = sm.u.p.sc[r][t];
        int   ix = sm.u.p.si[r][t];
        const float4 cv = *(const float4*)(cc + (long long)ix * D_DIM + dg * 4);
        o.x = fmaf(w2, cv.x, o.x);
        o.y = fmaf(w2, cv.y, o.y);
        o.z = fmaf(w2, cv.z, o.z);
        o.w = fmaf(w2, cv.w, o.w);
      }
      *(float4*)(out + base) = o;
    }
  }
}

extern "C" void kernel_launch(void* const* d_in, const int* in_sizes, int n_in,
                              void* d_out, int out_size, void* d_ws, size_t ws_size,
                              hipStream_t stream) {
  const float* x  = (const float*)d_in[0];
  const float* cc = (const float*)d_in[1];
  float* out = (float*)d_out;

  float* ct;
  if (d_ws != nullptr && ws_size >= CT_BYTES) {
    ct = (float*)d_ws;
  } else {
    void* p = nullptr;
    hipGetSymbolAddress(&p, HIP_SYMBOL(g_ct_fallback));
    ct = (float*)p;
  }

  const int Btot = in_sizes[0] / D_DIM;   // 131072
  const int grid = Btot / BM;             // 1024 = 4 blocks/CU x 256 CU, no tail
  transpose_c<<<dim3(D_DIM), dim3(128), 0, stream>>>(cc, ct);
  tse_fused<<<dim3(grid), dim3(NTHREADS), 0, stream>>>(x, cc, ct, out);
}